// Round 3
// baseline (51.851 us; speedup 1.0000x reference)
//
#include <hip/hip_runtime.h>
#include <math.h>

// Problem constants (fixed shapes from reference)
#define BATCH   8
#define HGRID   64
#define WGRID   64
#define DDIM    256
#define NPTS    1024
#define ROWS    65          // HGRID + 1 (NaN pad row 0)
#define COLS    65
#define KWIN    15          // (2*R_WIN+1)*(2*C_WIN+1) = 3*5
#define BN      (BATCH*NPTS)

typedef __attribute__((ext_vector_type(8))) short bf16x8;
typedef __attribute__((ext_vector_type(4))) float f32x4;

// ---------------------------------------------------------------------------
// Kernel 1: proj[m,d] = sum_c c_t[m,c] * W_a[c,d]   (M=8192, K=256, N=256)
// Split-bf16 3-term MFMA: x = xh + xl (bf16 each, lo exact residual);
// proj ~= Ch*Wh + Ch*Wl + Cl*Wh  (error ~2^-16 rel).
// Block = 256 thr (4 waves). BM=64 (16 rows/wave), BN=128. Grid (128, 2).
// W k-tile staged fp32 in LDS; B-frags gathered k-contiguous per lane.
// ---------------------------------------------------------------------------
__global__ __launch_bounds__(256) void proj_gemm_mfma(const float* __restrict__ C,
                                                      const float* __restrict__ W,
                                                      float* __restrict__ P) {
    __shared__ float Ws[32][132];          // [c-local][d-local], pitch 132 (16B-aligned)
    const int t    = threadIdx.x;
    const int lane = t & 63;
    const int wv   = t >> 6;
    const int l15  = lane & 15;
    const int g    = lane >> 4;            // k-group 0..3
    const int mrow = blockIdx.x * 64 + wv * 16 + l15;   // A row this lane loads
    const int dblk = blockIdx.y * 128;

    f32x4 acc[8];
    #pragma unroll
    for (int df = 0; df < 8; ++df) acc[df] = (f32x4)0.0f;

    for (int kt = 0; kt < 8; ++kt) {
        __syncthreads();                    // previous-iter reads done
        #pragma unroll
        for (int p = 0; p < 4; ++p) {
            int idx = p * 256 + t;          // 1024 float4 slots = 32x128 floats
            int row = idx >> 5;             // 32 float4 per c-row
            int c4  = (idx & 31) * 4;
            *reinterpret_cast<float4*>(&Ws[row][c4]) =
                *reinterpret_cast<const float4*>(&W[(kt * 32 + row) * DDIM + dblk + c4]);
        }
        __syncthreads();

        // ---- A fragment: 8 contiguous k (c) values of this lane's row ----
        const float* arow = &C[(size_t)mrow * DDIM + kt * 32 + g * 8];
        float4 a01 = *reinterpret_cast<const float4*>(arow);
        float4 a23 = *reinterpret_cast<const float4*>(arow + 4);
        float af[8] = {a01.x, a01.y, a01.z, a01.w, a23.x, a23.y, a23.z, a23.w};
        union { bf16x8 v; unsigned u[4]; } AH, AL;
        #pragma unroll
        for (int i = 0; i < 4; ++i) {
            unsigned u0 = __float_as_uint(af[2 * i]);
            unsigned u1 = __float_as_uint(af[2 * i + 1]);
            AH.u[i] = __builtin_amdgcn_perm(u1, u0, 0x07060302u);
            float l0 = af[2 * i]     - __uint_as_float(u0 & 0xFFFF0000u);
            float l1 = af[2 * i + 1] - __uint_as_float(u1 & 0xFFFF0000u);
            AL.u[i] = __builtin_amdgcn_perm(__float_as_uint(l1), __float_as_uint(l0),
                                            0x07060302u);
        }

        // ---- per d-frag: gather B (k-contiguous), split, 3 MFMA ----
        #pragma unroll
        for (int df = 0; df < 8; ++df) {
            float bf[8];
            #pragma unroll
            for (int i = 0; i < 8; ++i)
                bf[i] = Ws[g * 8 + i][df * 16 + l15];
            union { bf16x8 v; unsigned u[4]; } BH, BL;
            #pragma unroll
            for (int i = 0; i < 4; ++i) {
                unsigned u0 = __float_as_uint(bf[2 * i]);
                unsigned u1 = __float_as_uint(bf[2 * i + 1]);
                BH.u[i] = __builtin_amdgcn_perm(u1, u0, 0x07060302u);
                float l0 = bf[2 * i]     - __uint_as_float(u0 & 0xFFFF0000u);
                float l1 = bf[2 * i + 1] - __uint_as_float(u1 & 0xFFFF0000u);
                BL.u[i] = __builtin_amdgcn_perm(__float_as_uint(l1), __float_as_uint(l0),
                                                0x07060302u);
            }
            acc[df] = __builtin_amdgcn_mfma_f32_16x16x32_bf16(AH.v, BH.v, acc[df], 0, 0, 0);
            acc[df] = __builtin_amdgcn_mfma_f32_16x16x32_bf16(AH.v, BL.v, acc[df], 0, 0, 0);
            acc[df] = __builtin_amdgcn_mfma_f32_16x16x32_bf16(AL.v, BH.v, acc[df], 0, 0, 0);
        }
    }

    // C/D layout: col = lane&15, row = (lane>>4)*4 + reg  [m89-verified]
    #pragma unroll
    for (int df = 0; df < 8; ++df)
        #pragma unroll
        for (int r = 0; r < 4; ++r)
            P[(size_t)(blockIdx.x * 64 + wv * 16 + g * 4 + r) * DDIM
              + dblk + df * 16 + l15] = acc[df][r];
}

// ---------------------------------------------------------------------------
// Kernel 2: one wave per (b,n) point. Lane owns d = lane*4..+3 (float4).
// fp32 qg in registers (60 VGPR), __expf, no register cap.
// ---------------------------------------------------------------------------
__global__ __launch_bounds__(256) void local_attn(const float* __restrict__ q,
                                                  const float* __restrict__ p_t,
                                                  const float* __restrict__ proj,
                                                  float* __restrict__ out) {
    const int wave = threadIdx.x >> 6;
    const int lane = threadIdx.x & 63;
    const int pid  = blockIdx.x * 4 + wave;      // 0..8191
    const int b    = pid >> 10;                  // / NPTS
    const float2 pp = *reinterpret_cast<const float2*>(&p_t[pid * 2]);
    const float p0f = pp.x;
    const float p1f = pp.y;
    const int p0 = (int)p0f;                     // truncation == floor (nonneg)
    const int p1 = (int)p1f;

    const float4 pr = *reinterpret_cast<const float4*>(&proj[(size_t)pid * DDIM + lane * 4]);

    float re[3], ce[5];
    int rowidx[3], colidx[5];

    #pragma unroll
    for (int i = 0; i < 3; ++i) {
        int rr = p0 + i;                          // in [0,64]
        rr = rr > ROWS ? ROWS : rr;
        rr = (rr == ROWS) ? 0 : rr;               // % ROWS
        rowidx[i] = rr;
        const float rf = (float)(rr - 1 > 0 ? rr - 1 : 0);
        const float dr = rf - p0f;                // / R_WIN (=1)
        re[i] = __expf(-2.0f * dr * dr);
    }
    #pragma unroll
    for (int j = 0; j < 5; ++j) {
        int cc = p1 + j - 1;
        cc = cc < 0 ? 0 : (cc > COLS ? COLS : cc);
        cc = (cc == COLS) ? 0 : cc;               // % COLS
        colidx[j] = cc;
        const float cf = (float)(cc - 1 > 0 ? cc - 1 : 0);
        const float dc = (cf - p1f) * 0.5f;       // / C_WIN (=2)
        ce[j] = __expf(-2.0f * dc * dc);
    }

    float4 qg[KWIN];
    float score[KWIN];
    unsigned vmask = 0;

    // Pass 1: gather + dot partials (loads independent -> MLP)
    #pragma unroll
    for (int i = 0; i < 3; ++i) {
        #pragma unroll
        for (int j = 0; j < 5; ++j) {
            const int k  = i * 5 + j;
            const int rr = rowidx[i];
            const int cc = colidx[j];
            const bool valid = (rr != 0) && (cc != 0);    // wave-uniform
            float s = 0.f;
            float4 v = make_float4(0.f, 0.f, 0.f, 0.f);
            if (valid) {
                v = *reinterpret_cast<const float4*>(
                    &q[((size_t)((b * HGRID + rr - 1) * WGRID + cc - 1)) * DDIM + lane * 4]);
                s = fmaf(v.x, pr.x, fmaf(v.y, pr.y, fmaf(v.z, pr.z, v.w * pr.w)));
                vmask |= (1u << k);
            }
            qg[k] = v;
            score[k] = s;
        }
    }

    // Pass 2: wave-64 butterfly reduce each score
    #pragma unroll
    for (int k = 0; k < KWIN; ++k) {
        float s = score[k];
        #pragma unroll
        for (int off = 32; off; off >>= 1) s += __shfl_xor(s, off, 64);
        score[k] = ((vmask >> k) & 1u) ? s : -INFINITY;
    }

    // Softmax over K=15 (replicated identically across lanes)
    float mx = score[0];
    #pragma unroll
    for (int k = 1; k < KWIN; ++k) mx = fmaxf(mx, score[k]);
    float sum = 0.f;
    #pragma unroll
    for (int k = 0; k < KWIN; ++k) {
        const float e = __expf(score[k] - mx);
        score[k] = e;
        sum += e;
    }
    const float inv = 1.0f / sum;

    float ox = 0.f, oy = 0.f, oz = 0.f, ow = 0.f;
    #pragma unroll
    for (int i = 0; i < 3; ++i) {
        #pragma unroll
        for (int j = 0; j < 5; ++j) {
            const int k = i * 5 + j;
            const float wk = score[k] * inv * re[i] * ce[j];
            ox = fmaf(wk, qg[k].x, ox);
            oy = fmaf(wk, qg[k].y, oy);
            oz = fmaf(wk, qg[k].z, oz);
            ow = fmaf(wk, qg[k].w, ow);
        }
    }
    *reinterpret_cast<float4*>(&out[(size_t)pid * DDIM + lane * 4]) =
        make_float4(ox, oy, oz, ow);
}

// ---------------------------------------------------------------------------
extern "C" void kernel_launch(void* const* d_in, const int* in_sizes, int n_in,
                              void* d_out, int out_size, void* d_ws, size_t ws_size,
                              hipStream_t stream) {
    const float* q   = (const float*)d_in[0];
    const float* c_t = (const float*)d_in[1];
    const float* p_t = (const float*)d_in[2];
    const float* W_a = (const float*)d_in[3];
    float* out  = (float*)d_out;
    float* proj = (float*)d_ws;                 // BN*DDIM*4 = 8 MB scratch

    dim3 gemm_grid(BN / 64, DDIM / 128);        // 128 x 2
    proj_gemm_mfma<<<gemm_grid, 256, 0, stream>>>(c_t, W_a, proj);

    local_attn<<<BN / 4, 256, 0, stream>>>(q, p_t, proj, out);
}

// Round 4
// 39.420 us; speedup vs baseline: 1.3153x; 1.3153x over previous
//
#include <hip/hip_runtime.h>
#include <math.h>

// Problem constants (fixed shapes from reference)
#define BATCH   8
#define HGRID   64
#define WGRID   64
#define DDIM    256
#define NPTS    1024
#define ROWS    65          // HGRID + 1 (NaN pad row 0)
#define COLS    65
#define KWIN    15          // (2*R_WIN+1)*(2*C_WIN+1) = 3*5
#define BN      (BATCH*NPTS)

#define PIDS_PER_BLK 16
#define THREADS      512    // 8 waves
#define WS_PITCH     260    // 256 + 4 floats, 16B-aligned rows
#define PR_PITCH     260

typedef __attribute__((ext_vector_type(8))) short bf16x8;
typedef __attribute__((ext_vector_type(4))) float f32x4;

// ---------------------------------------------------------------------------
// Fully fused: per block of 16 points,
//   Phase A: proj[16][256] = c_t[16 rows] x W_a  (split-bf16 MFMA) -> LDS
//   Phase B: local windowed attention per point (2 pids / wave)   -> out
// ---------------------------------------------------------------------------
__global__ __launch_bounds__(THREADS) void fused_local_attn(
        const float* __restrict__ q,
        const float* __restrict__ c_t,
        const float* __restrict__ p_t,
        const float* __restrict__ W,
        float* __restrict__ out) {

    __shared__ __align__(16) float Ws[32][WS_PITCH];          // W_a k-tile
    __shared__ __align__(16) float Pr[PIDS_PER_BLK][PR_PITCH]; // proj rows

    const int t    = threadIdx.x;
    const int w    = t >> 6;          // wave 0..7
    const int lane = t & 63;
    const int l15  = lane & 15;
    const int g    = lane >> 4;       // k-group 0..3
    const int pid0 = blockIdx.x * PIDS_PER_BLK;
    const int dq   = w * 32;          // this wave's 32-col d-slice

    // ---------------- Phase A: proj into LDS ----------------
    f32x4 acc0 = (f32x4)0.f;
    f32x4 acc1 = (f32x4)0.f;

    for (int kt = 0; kt < 8; ++kt) {
        __syncthreads();              // previous-iter Ws readers done
        #pragma unroll
        for (int p = 0; p < 4; ++p) {
            const int idx = p * THREADS + t;       // 2048 float4 = 32 x 64
            const int row = idx >> 6;
            const int c4  = (idx & 63) * 4;
            *reinterpret_cast<float4*>(&Ws[row][c4]) =
                *reinterpret_cast<const float4*>(&W[(kt * 32 + row) * DDIM + c4]);
        }
        __syncthreads();

        // A fragment: 8 contiguous c-values of c_t row (pid0 + l15)
        const float* arow = &c_t[(size_t)(pid0 + l15) * DDIM + kt * 32 + g * 8];
        const float4 a01 = *reinterpret_cast<const float4*>(arow);
        const float4 a23 = *reinterpret_cast<const float4*>(arow + 4);
        const float af[8] = {a01.x, a01.y, a01.z, a01.w, a23.x, a23.y, a23.z, a23.w};
        union { bf16x8 v; unsigned u[4]; } AH, AL;
        #pragma unroll
        for (int i = 0; i < 4; ++i) {
            const unsigned u0 = __float_as_uint(af[2 * i]);
            const unsigned u1 = __float_as_uint(af[2 * i + 1]);
            AH.u[i] = __builtin_amdgcn_perm(u1, u0, 0x07060302u);
            const float l0 = af[2 * i]     - __uint_as_float(u0 & 0xFFFF0000u);
            const float l1 = af[2 * i + 1] - __uint_as_float(u1 & 0xFFFF0000u);
            AL.u[i] = __builtin_amdgcn_perm(__float_as_uint(l1), __float_as_uint(l0),
                                            0x07060302u);
        }

        #pragma unroll
        for (int df = 0; df < 2; ++df) {
            float bf[8];
            #pragma unroll
            for (int i = 0; i < 8; ++i)
                bf[i] = Ws[g * 8 + i][dq + df * 16 + l15];
            union { bf16x8 v; unsigned u[4]; } BH, BL;
            #pragma unroll
            for (int i = 0; i < 4; ++i) {
                const unsigned u0 = __float_as_uint(bf[2 * i]);
                const unsigned u1 = __float_as_uint(bf[2 * i + 1]);
                BH.u[i] = __builtin_amdgcn_perm(u1, u0, 0x07060302u);
                const float l0 = bf[2 * i]     - __uint_as_float(u0 & 0xFFFF0000u);
                const float l1 = bf[2 * i + 1] - __uint_as_float(u1 & 0xFFFF0000u);
                BL.u[i] = __builtin_amdgcn_perm(__float_as_uint(l1), __float_as_uint(l0),
                                                0x07060302u);
            }
            f32x4 a = (df == 0) ? acc0 : acc1;
            a = __builtin_amdgcn_mfma_f32_16x16x32_bf16(AH.v, BH.v, a, 0, 0, 0);
            a = __builtin_amdgcn_mfma_f32_16x16x32_bf16(AH.v, BL.v, a, 0, 0, 0);
            a = __builtin_amdgcn_mfma_f32_16x16x32_bf16(AL.v, BH.v, a, 0, 0, 0);
            if (df == 0) acc0 = a; else acc1 = a;
        }
    }

    // C/D layout: col = lane&15, row = (lane>>4)*4 + reg  [m89-verified]
    #pragma unroll
    for (int r = 0; r < 4; ++r) {
        Pr[g * 4 + r][dq +  0 + l15] = acc0[r];
        Pr[g * 4 + r][dq + 16 + l15] = acc1[r];
    }
    __syncthreads();

    // ---------------- Phase B: attention, 2 pids per wave ----------------
    #pragma unroll 1
    for (int pp = 0; pp < 2; ++pp) {
        const int pl  = w * 2 + pp;            // pid-local 0..15
        const int pid = pid0 + pl;
        const int b   = pid >> 10;             // / NPTS
        const float2 ppos = *reinterpret_cast<const float2*>(&p_t[pid * 2]);
        const float p0f = ppos.x;
        const float p1f = ppos.y;
        const int p0 = (int)p0f;
        const int p1 = (int)p1f;

        const float4 pr = *reinterpret_cast<const float4*>(&Pr[pl][lane * 4]);

        float re[3], ce[5];
        int rowidx[3], colidx[5];
        #pragma unroll
        for (int i = 0; i < 3; ++i) {
            int rr = p0 + i;
            rr = rr > ROWS ? ROWS : rr;
            rr = (rr == ROWS) ? 0 : rr;        // % ROWS
            rowidx[i] = rr;
            const float rf = (float)(rr - 1 > 0 ? rr - 1 : 0);
            const float dr = rf - p0f;         // / R_WIN (=1)
            re[i] = __expf(-2.0f * dr * dr);
        }
        #pragma unroll
        for (int j = 0; j < 5; ++j) {
            int cc = p1 + j - 1;
            cc = cc < 0 ? 0 : (cc > COLS ? COLS : cc);
            cc = (cc == COLS) ? 0 : cc;        // % COLS
            colidx[j] = cc;
            const float cf = (float)(cc - 1 > 0 ? cc - 1 : 0);
            const float dc = (cf - p1f) * 0.5f; // / C_WIN (=2)
            ce[j] = __expf(-2.0f * dc * dc);
        }

        float4 qg[KWIN];
        float score[KWIN];
        unsigned vmask = 0;

        #pragma unroll
        for (int i = 0; i < 3; ++i) {
            #pragma unroll
            for (int j = 0; j < 5; ++j) {
                const int k  = i * 5 + j;
                const int rr = rowidx[i];
                const int cc = colidx[j];
                const bool valid = (rr != 0) && (cc != 0);   // wave-uniform
                float s = 0.f;
                float4 v = make_float4(0.f, 0.f, 0.f, 0.f);
                if (valid) {
                    v = *reinterpret_cast<const float4*>(
                        &q[((size_t)((b * HGRID + rr - 1) * WGRID + cc - 1)) * DDIM
                           + lane * 4]);
                    s = fmaf(v.x, pr.x, fmaf(v.y, pr.y, fmaf(v.z, pr.z, v.w * pr.w)));
                    vmask |= (1u << k);
                }
                qg[k] = v;
                score[k] = s;
            }
        }

        #pragma unroll
        for (int k = 0; k < KWIN; ++k) {
            float s = score[k];
            #pragma unroll
            for (int off = 32; off; off >>= 1) s += __shfl_xor(s, off, 64);
            score[k] = ((vmask >> k) & 1u) ? s : -INFINITY;
        }

        float mx = score[0];
        #pragma unroll
        for (int k = 1; k < KWIN; ++k) mx = fmaxf(mx, score[k]);
        float sum = 0.f;
        #pragma unroll
        for (int k = 0; k < KWIN; ++k) {
            const float e = __expf(score[k] - mx);
            score[k] = e;
            sum += e;
        }
        const float inv = 1.0f / sum;

        float ox = 0.f, oy = 0.f, oz = 0.f, ow = 0.f;
        #pragma unroll
        for (int i = 0; i < 3; ++i) {
            #pragma unroll
            for (int j = 0; j < 5; ++j) {
                const int k = i * 5 + j;
                const float wk = score[k] * inv * re[i] * ce[j];
                ox = fmaf(wk, qg[k].x, ox);
                oy = fmaf(wk, qg[k].y, oy);
                oz = fmaf(wk, qg[k].z, oz);
                ow = fmaf(wk, qg[k].w, ow);
            }
        }
        *reinterpret_cast<float4*>(&out[(size_t)pid * DDIM + lane * 4]) =
            make_float4(ox, oy, oz, ow);
    }
}

// ---------------------------------------------------------------------------
extern "C" void kernel_launch(void* const* d_in, const int* in_sizes, int n_in,
                              void* d_out, int out_size, void* d_ws, size_t ws_size,
                              hipStream_t stream) {
    const float* q   = (const float*)d_in[0];
    const float* c_t = (const float*)d_in[1];
    const float* p_t = (const float*)d_in[2];
    const float* W_a = (const float*)d_in[3];
    float* out = (float*)d_out;

    fused_local_attn<<<BN / PIDS_PER_BLK, THREADS, 0, stream>>>(q, c_t, p_t, W_a, out);
}

// Round 5
// 36.443 us; speedup vs baseline: 1.4228x; 1.0817x over previous
//
#include <hip/hip_runtime.h>
#include <math.h>

// Problem constants (fixed shapes from reference)
#define BATCH   8
#define HGRID   64
#define WGRID   64
#define DDIM    256
#define NPTS    1024
#define ROWS    65          // HGRID + 1 (NaN pad row 0)
#define COLS    65
#define KWIN    15          // (2*R_WIN+1)*(2*C_WIN+1) = 3*5
#define BN      (BATCH*NPTS)

#define PIDS_PER_BLK 16
#define THREADS      512    // 8 waves
#define PR_PITCH     260

typedef __attribute__((ext_vector_type(8))) short bf16x8;
typedef __attribute__((ext_vector_type(4))) float f32x4;

// ---------------------------------------------------------------------------
// Fused v2: per block of 16 points,
//   Phase A (straight-line, NO barriers): proj[16][256] = c_t rows x W_a
//     split-bf16 MFMA; W read per-wave from global (L2-hot), wave owns 32 cols
//   one __syncthreads()
//   Phase B: local windowed attention, 2 pids per wave
// __launch_bounds__(512,4): cap 128 VGPR -> 4 waves/SIMD, no spills (est ~115)
// ---------------------------------------------------------------------------
__global__ __launch_bounds__(THREADS, 4) void fused_local_attn(
        const float* __restrict__ q,
        const float* __restrict__ c_t,
        const float* __restrict__ p_t,
        const float* __restrict__ W,
        float* __restrict__ out) {

    __shared__ __align__(16) float Pr[PIDS_PER_BLK][PR_PITCH]; // proj rows

    const int t    = threadIdx.x;
    const int w    = t >> 6;          // wave 0..7
    const int lane = t & 63;
    const int l15  = lane & 15;
    const int g    = lane >> 4;       // k-group 0..3
    const int pid0 = blockIdx.x * PIDS_PER_BLK;
    const int dq   = w * 32;          // this wave's 32-col d-slice

    // ---------------- Phase A: proj into LDS (no barriers) ----------------
    f32x4 acc0 = (f32x4)0.f;
    f32x4 acc1 = (f32x4)0.f;

    const float* ap  = &c_t[(size_t)(pid0 + l15) * DDIM + g * 8];
    const float* wp0 = &W[(size_t)(g * 8) * DDIM + dq + l15];        // df=0
    const float* wp1 = wp0 + 16;                                      // df=1

    #pragma unroll 2
    for (int kt = 0; kt < 8; ++kt) {
        // A fragment: 8 contiguous c-values of c_t row (pid0 + l15)
        const float4 a01 = *reinterpret_cast<const float4*>(ap + kt * 32);
        const float4 a23 = *reinterpret_cast<const float4*>(ap + kt * 32 + 4);
        const float af[8] = {a01.x, a01.y, a01.z, a01.w, a23.x, a23.y, a23.z, a23.w};
        union { bf16x8 v; unsigned u[4]; } AH, AL;
        #pragma unroll
        for (int i = 0; i < 4; ++i) {
            const unsigned u0 = __float_as_uint(af[2 * i]);
            const unsigned u1 = __float_as_uint(af[2 * i + 1]);
            AH.u[i] = __builtin_amdgcn_perm(u1, u0, 0x07060302u);
            const float l0 = af[2 * i]     - __uint_as_float(u0 & 0xFFFF0000u);
            const float l1 = af[2 * i + 1] - __uint_as_float(u1 & 0xFFFF0000u);
            AL.u[i] = __builtin_amdgcn_perm(__float_as_uint(l1), __float_as_uint(l0),
                                            0x07060302u);
        }

        #pragma unroll
        for (int df = 0; df < 2; ++df) {
            const float* wp = (df == 0) ? wp0 : wp1;
            float bf[8];
            #pragma unroll
            for (int i = 0; i < 8; ++i)
                bf[i] = wp[(size_t)(kt * 32 + i) * DDIM];
            union { bf16x8 v; unsigned u[4]; } BH, BL;
            #pragma unroll
            for (int i = 0; i < 4; ++i) {
                const unsigned u0 = __float_as_uint(bf[2 * i]);
                const unsigned u1 = __float_as_uint(bf[2 * i + 1]);
                BH.u[i] = __builtin_amdgcn_perm(u1, u0, 0x07060302u);
                const float l0 = bf[2 * i]     - __uint_as_float(u0 & 0xFFFF0000u);
                const float l1 = bf[2 * i + 1] - __uint_as_float(u1 & 0xFFFF0000u);
                BL.u[i] = __builtin_amdgcn_perm(__float_as_uint(l1), __float_as_uint(l0),
                                                0x07060302u);
            }
            f32x4 a = (df == 0) ? acc0 : acc1;
            a = __builtin_amdgcn_mfma_f32_16x16x32_bf16(AH.v, BH.v, a, 0, 0, 0);
            a = __builtin_amdgcn_mfma_f32_16x16x32_bf16(AH.v, BL.v, a, 0, 0, 0);
            a = __builtin_amdgcn_mfma_f32_16x16x32_bf16(AL.v, BH.v, a, 0, 0, 0);
            if (df == 0) acc0 = a; else acc1 = a;
        }
    }

    // C/D layout: col = lane&15, row = (lane>>4)*4 + reg  [m89-verified]
    #pragma unroll
    for (int r = 0; r < 4; ++r) {
        Pr[g * 4 + r][dq +  0 + l15] = acc0[r];
        Pr[g * 4 + r][dq + 16 + l15] = acc1[r];
    }
    __syncthreads();

    // ---------------- Phase B: attention, 2 pids per wave ----------------
    #pragma unroll 1
    for (int pp = 0; pp < 2; ++pp) {
        const int pl  = w * 2 + pp;            // pid-local 0..15
        const int pid = pid0 + pl;
        const int b   = pid >> 10;             // / NPTS
        const float2 ppos = *reinterpret_cast<const float2*>(&p_t[pid * 2]);
        const float p0f = ppos.x;
        const float p1f = ppos.y;
        const int p0 = (int)p0f;
        const int p1 = (int)p1f;

        const float4 pr = *reinterpret_cast<const float4*>(&Pr[pl][lane * 4]);

        float re[3], ce[5];
        int rowidx[3], colidx[5];
        #pragma unroll
        for (int i = 0; i < 3; ++i) {
            int rr = p0 + i;
            rr = rr > ROWS ? ROWS : rr;
            rr = (rr == ROWS) ? 0 : rr;        // % ROWS
            rowidx[i] = rr;
            const float rf = (float)(rr - 1 > 0 ? rr - 1 : 0);
            const float dr = rf - p0f;         // / R_WIN (=1)
            re[i] = __expf(-2.0f * dr * dr);
        }
        #pragma unroll
        for (int j = 0; j < 5; ++j) {
            int cc = p1 + j - 1;
            cc = cc < 0 ? 0 : (cc > COLS ? COLS : cc);
            cc = (cc == COLS) ? 0 : cc;        // % COLS
            colidx[j] = cc;
            const float cf = (float)(cc - 1 > 0 ? cc - 1 : 0);
            const float dc = (cf - p1f) * 0.5f; // / C_WIN (=2)
            ce[j] = __expf(-2.0f * dc * dc);
        }

        float4 qg[KWIN];
        float score[KWIN];
        unsigned vmask = 0;

        #pragma unroll
        for (int i = 0; i < 3; ++i) {
            #pragma unroll
            for (int j = 0; j < 5; ++j) {
                const int k  = i * 5 + j;
                const int rr = rowidx[i];
                const int cc = colidx[j];
                const bool valid = (rr != 0) && (cc != 0);   // wave-uniform
                float s = 0.f;
                float4 v = make_float4(0.f, 0.f, 0.f, 0.f);
                if (valid) {
                    v = *reinterpret_cast<const float4*>(
                        &q[((size_t)((b * HGRID + rr - 1) * WGRID + cc - 1)) * DDIM
                           + lane * 4]);
                    s = fmaf(v.x, pr.x, fmaf(v.y, pr.y, fmaf(v.z, pr.z, v.w * pr.w)));
                    vmask |= (1u << k);
                }
                qg[k] = v;
                score[k] = s;
            }
        }

        #pragma unroll
        for (int k = 0; k < KWIN; ++k) {
            float s = score[k];
            #pragma unroll
            for (int off = 32; off; off >>= 1) s += __shfl_xor(s, off, 64);
            score[k] = ((vmask >> k) & 1u) ? s : -INFINITY;
        }

        float mx = score[0];
        #pragma unroll
        for (int k = 1; k < KWIN; ++k) mx = fmaxf(mx, score[k]);
        float sum = 0.f;
        #pragma unroll
        for (int k = 0; k < KWIN; ++k) {
            const float e = __expf(score[k] - mx);
            score[k] = e;
            sum += e;
        }
        const float inv = 1.0f / sum;

        float ox = 0.f, oy = 0.f, oz = 0.f, ow = 0.f;
        #pragma unroll
        for (int i = 0; i < 3; ++i) {
            #pragma unroll
            for (int j = 0; j < 5; ++j) {
                const int k = i * 5 + j;
                const float wk = score[k] * inv * re[i] * ce[j];
                ox = fmaf(wk, qg[k].x, ox);
                oy = fmaf(wk, qg[k].y, oy);
                oz = fmaf(wk, qg[k].z, oz);
                ow = fmaf(wk, qg[k].w, ow);
            }
        }
        *reinterpret_cast<float4*>(&out[(size_t)pid * DDIM + lane * 4]) =
            make_float4(ox, oy, oz, ow);
    }
}

// ---------------------------------------------------------------------------
extern "C" void kernel_launch(void* const* d_in, const int* in_sizes, int n_in,
                              void* d_out, int out_size, void* d_ws, size_t ws_size,
                              hipStream_t stream) {
    const float* q   = (const float*)d_in[0];
    const float* c_t = (const float*)d_in[1];
    const float* p_t = (const float*)d_in[2];
    const float* W_a = (const float*)d_in[3];
    float* out = (float*)d_out;

    fused_local_attn<<<BN / PIDS_PER_BLK, THREADS, 0, stream>>>(q, c_t, p_t, W_a, out);
}